// Round 11
// baseline (688.589 us; speedup 1.0000x reference)
//
#include <hip/hip_runtime.h>

// Problem constants (match reference)
#define NN 100000
#define TT 128
#define EE 1600000
#define KK 9

// Binned CSR build: 512-node buckets
#define BSH 9
#define BMASK 511
#define NBUCK 196                 // ceil(100000/512)
#define BCAP 10240                // avg 8163/bucket, sigma~90 -> 23 sigma headroom
#define EPB 4096                  // edges per bin block
#define BINB 391                  // ceil(EE/EPB)
#define CVTB 3125                 // NN*TT/4 / 1024

typedef _Float16 f16;
typedef __attribute__((ext_vector_type(4))) _Float16 f16x4;
typedef __attribute__((ext_vector_type(8))) _Float16 f16x8;

union HU8 { f16x8 h; int4 i; };

// ---------- fused: bin edges (blocks 0..BINB) + x fp32->fp16 + init out=bias ----------
// Packed edge: (dlocal << 20) | src   (src < 2^17, dlocal < 2^9)
__global__ __launch_bounds__(1024)
void bin_cvt_kernel(const int* __restrict__ ei, int* __restrict__ gcursor,
                    unsigned int* __restrict__ binned,
                    const float4* __restrict__ x, f16x4* __restrict__ x16,
                    const float* __restrict__ bout, float* __restrict__ out) {
    __shared__ int hist[NBUCK];
    __shared__ int gbase[NBUCK];
    int tid = threadIdx.x;

    if (blockIdx.x >= BINB + CVTB) {          // one block: init out with the bias
        if (tid < TT * 3) out[tid] = bout[tid - (tid / 3) * 3];
        return;
    }
    if (blockIdx.x >= BINB) {
        // cvt part: one float4 per thread over N*T/4 (exactly CVTB*1024 elements)
        int i = (blockIdx.x - BINB) * 1024 + tid;
        float4 v = x[i];
        f16x4 o;
        o.x = (f16)v.x; o.y = (f16)v.y; o.z = (f16)v.z; o.w = (f16)v.w;
        x16[i] = o;
        return;
    }

    if (tid < NBUCK) hist[tid] = 0;
    __syncthreads();
    int base = blockIdx.x * EPB;
    unsigned int val[4];
    short bkt[4];
    short rank[4];
#pragma unroll
    for (int k = 0; k < 4; k++) {
        int e = base + k * 1024 + tid;
        bkt[k] = -1;
        if (e < EE) {
            int s = ei[e];            // src
            int d = ei[EE + e];       // dst
            bkt[k] = (short)(d >> BSH);
            val[k] = ((unsigned int)(d & BMASK) << 20) | (unsigned int)s;
            rank[k] = (short)atomicAdd(&hist[bkt[k]], 1);
        }
    }
    __syncthreads();
    if (tid < NBUCK) gbase[tid] = hist[tid] ? atomicAdd(&gcursor[tid], hist[tid]) : 0;
    __syncthreads();
#pragma unroll
    for (int k = 0; k < 4; k++) {
        if (bkt[k] >= 0)
            binned[(size_t)bkt[k] * BCAP + gbase[bkt[k]] + (int)rank[k]] = val[k];
    }
}

// ---------- per-bucket (512 nodes): bucket-base scan + hist + scan + offsets/inv_cnt + place ----------
__global__ __launch_bounds__(1024)
void bucket_csr_kernel(const unsigned int* __restrict__ binned,
                       const int* __restrict__ gcursor,
                       int* __restrict__ offsets,
                       float* __restrict__ inv_cnt,
                       int* __restrict__ col) {
    __shared__ int hist[512];
    __shared__ int cur[512];
    __shared__ int smB[256];
    __shared__ int sc[512];
    int b = blockIdx.x;
    int tid = threadIdx.x;

    // bucket-base scan over all 196 bucket counts (threads 0..255; ~µs)
    if (tid < 256) smB[tid] = (tid < NBUCK) ? gcursor[tid] : 0;
    __syncthreads();
    for (int off = 1; off < 256; off <<= 1) {
        int v = 0;
        if (tid < 256 && tid >= off) v = smB[tid - off];
        __syncthreads();
        if (tid < 256) smB[tid] += v;
        __syncthreads();
    }
    int bucket_base = (b == 0) ? 0 : smB[b - 1];
    if (b == 0 && tid == 0) offsets[NN] = EE;

    int cnt = gcursor[b];
    const unsigned int* ePtr = binned + (size_t)b * BCAP;
    if (tid < 512) hist[tid] = 0;
    __syncthreads();
    for (int j = tid; j < cnt; j += 1024)          // ~8 iterations
        atomicAdd(&hist[ePtr[j] >> 20], 1);
    __syncthreads();
    int d = (tid < 512) ? hist[tid] : 0;
    if (tid < 512) sc[tid] = d;
    __syncthreads();
    for (int off = 1; off < 512; off <<= 1) {      // inclusive scan of 512 degrees
        int v = 0;
        if (tid < 512 && tid >= off) v = sc[tid - off];
        __syncthreads();
        if (tid < 512) sc[tid] += v;
        __syncthreads();
    }
    if (tid < 512) {
        int node = (b << BSH) + tid;
        int pos = bucket_base + sc[tid] - d;       // exclusive prefix
        if (node < NN) {
            offsets[node] = pos;
            inv_cnt[node] = 1.0f / (1.0f + (float)d);
            cur[tid] = pos;
        }
    }
    __syncthreads();
    // place: all writes land in this bucket's contiguous col window (~32 KB, L2-resident)
    for (int j = tid; j < cnt; j += 1024) {        // ~8 iterations
        unsigned int v = ePtr[j];
        int pos = atomicAdd(&cur[v >> 20], 1);
        col[pos] = (int)(v & 0xFFFFF);
    }
}

// ---------- shared gather+conv body (one wave per node) ----------
// p = lane&15 owns t = {8p..8p+7} (f16x8, 16B); quarter-groups q process 4 edges
// per 1 KiB load; packed-fp16 accumulate; xor-16/32 combine; fp32 conv epilogue.
// Result: s[0..7] = relu(conv(...)*ic + b) for t = 8p..8p+7, valid on ALL lanes.
__device__ __forceinline__ void gather_conv_node(
    const f16x8* __restrict__ xin, const int* __restrict__ offsets,
    const int* __restrict__ col, const float* __restrict__ inv_cnt,
    const float* wr, float bb, int node, int lane, int q, int p, float* s)
{
    int lo = offsets[node], hi = offsets[node + 1];
    int cnt = hi - lo;
    int my_col = (lane < cnt) ? col[lo + lane] : 0;
    int jn = cnt < 64 ? cnt : 64;

    const f16 z = (f16)0;
    f16x8 acc0 = {z, z, z, z, z, z, z, z};
    f16x8 acc1 = {z, z, z, z, z, z, z, z};

    int j = 0;
    for (; j + 7 < jn; j += 8) {               // 8 edges / iter, 2 loads in flight
        int c0 = __shfl(my_col, j + q);
        int c1 = __shfl(my_col, j + 4 + q);
        f16x8 v0 = xin[(c0 << 4) | p];
        f16x8 v1 = xin[(c1 << 4) | p];
        acc0 += v0;
        acc1 += v1;
    }
    for (; j + 3 < jn; j += 4) {               // 4 edges
        int c = __shfl(my_col, j + q);
        acc0 += xin[(c << 4) | p];
    }
    if (j < jn) {                              // tail 1..3 edges
        int rem = jn - j;
        int c = __shfl(my_col, j + (q < rem ? q : 0));
        f16x8 v = xin[(c << 4) | p];
        if (q < rem) acc1 += v;
    }
    for (int k = 64; k < cnt; k++) {           // degree > 64 (effectively never)
        int c = col[lo + k];
        f16x8 v = xin[(c << 4) | p];
        if (q == 0) acc0 += v;
    }
    acc0 += acc1;

    {   // combine the 4 quarter-groups: xor-16 then xor-32
        HU8 u; u.h = acc0;
        int4 o;
        o.x = __shfl_xor(u.i.x, 16); o.y = __shfl_xor(u.i.y, 16);
        o.z = __shfl_xor(u.i.z, 16); o.w = __shfl_xor(u.i.w, 16);
        HU8 w2; w2.i = o;
        acc0 += w2.h;
        u.h = acc0;
        o.x = __shfl_xor(u.i.x, 32); o.y = __shfl_xor(u.i.y, 32);
        o.z = __shfl_xor(u.i.z, 32); o.w = __shfl_xor(u.i.w, 32);
        w2.i = o;
        acc0 += w2.h;
    }

    // fp32 epilogue: + self row, conv K=9, mean, bias, relu
    f16x8 sv = xin[(node << 4) | p];
    float A[16];
    A[4]  = (float)acc0[0] + (float)sv[0];
    A[5]  = (float)acc0[1] + (float)sv[1];
    A[6]  = (float)acc0[2] + (float)sv[2];
    A[7]  = (float)acc0[3] + (float)sv[3];
    A[8]  = (float)acc0[4] + (float)sv[4];
    A[9]  = (float)acc0[5] + (float)sv[5];
    A[10] = (float)acc0[6] + (float)sv[6];
    A[11] = (float)acc0[7] + (float)sv[7];
#pragma unroll
    for (int i = 0; i < 4; i++) {
        A[i]      = __shfl_up(A[8 + i], 1, 16);    // prev lane's a[4..7]
        A[12 + i] = __shfl_down(A[4 + i], 1, 16);  // next lane's a[0..3]
    }
    if (p == 0)  { A[0] = 0.0f; A[1] = 0.0f; A[2] = 0.0f; A[3] = 0.0f; }
    if (p == 15) { A[12] = 0.0f; A[13] = 0.0f; A[14] = 0.0f; A[15] = 0.0f; }

    float ic = inv_cnt[node];
#pragma unroll
    for (int i = 0; i < 8; i++) {
        float t = 0.0f;
#pragma unroll
        for (int k = 0; k < KK; k++) t += wr[k] * A[i + k];
        s[i] = fmaxf(t * ic + bb, 0.0f);
    }
}

// ---------- layers 1-2: store y as f16x8 (one wave per node, one-shot blocks) ----------
__global__ void fused_layer_kernel(const f16x8* __restrict__ xin,
                                   const int* __restrict__ offsets,
                                   const int* __restrict__ col,
                                   const float* __restrict__ inv_cnt,
                                   const float* __restrict__ w9,
                                   const float* __restrict__ bptr,
                                   f16x8* __restrict__ yout) {
    int tid = threadIdx.x;
    int lane = tid & 63;
    int q = lane >> 4;
    int p = lane & 15;
    int node = blockIdx.x * 4 + (tid >> 6);
    float wr[KK];
#pragma unroll
    for (int k = 0; k < KK; k++) wr[k] = w9[k];
    float s[8];
    gather_conv_node(xin, offsets, col, inv_cnt, wr, bptr[0], node, lane, q, p, s);
    if (q == 0) {
        f16x8 o;
#pragma unroll
        for (int i = 0; i < 8; i++) o[i] = (f16)s[i];
        yout[(node << 4) | p] = o;
    }
}

// ---------- layer 3 fused with output head (one-shot blocks, same shape as L1/L2) ----------
// Reference: out = y3.reshape(-1,N) @ Wout.T — FLAT reinterpretation. Node n's row sits
// at flat f = n*128+tt -> out row t0 = f/NN (constant per non-boundary node), Wout col
// run r0..r0+127. All 4 quarter-groups hold the full row after the xor combines, so
// quarter q in {0,1,2} owns channel q: 8 FMAs + width-16 reduce + 1 global atomic.
__global__ void layer3_out_kernel(const f16x8* __restrict__ xin,
                                  const int* __restrict__ offsets,
                                  const int* __restrict__ col,
                                  const float* __restrict__ inv_cnt,
                                  const float* __restrict__ w9,
                                  const float* __restrict__ bptr,
                                  const float* __restrict__ Wout,
                                  float* __restrict__ out) {
    int tid = threadIdx.x;
    int lane = tid & 63;
    int q = lane >> 4;
    int p = lane & 15;
    int node = blockIdx.x * 4 + (tid >> 6);
    float wr[KK];
#pragma unroll
    for (int k = 0; k < KK; k++) wr[k] = w9[k];
    float s[8];
    gather_conv_node(xin, offsets, col, inv_cnt, wr, bptr[0], node, lane, q, p, s);

    int f0 = node * TT;        // flat base index of this node's row
    int t0 = f0 / NN;          // output row
    int r0 = f0 - t0 * NN;     // Wout column base (multiple of 32)
    if (r0 + TT <= NN) {
        // fast path: whole row maps to out[t0][*]
        if (q < 3) {
            const float4* Wrow = (const float4*)(Wout + q * NN + r0 + 8 * p);
            float4 w0 = Wrow[0];
            float4 w1 = Wrow[1];
            float a = s[0] * w0.x + s[1] * w0.y + s[2] * w0.z + s[3] * w0.w
                    + s[4] * w1.x + s[5] * w1.y + s[6] * w1.z + s[7] * w1.w;
            for (int o = 8; o > 0; o >>= 1) a += __shfl_down(a, o, 16);
            if (p == 0) atomicAdd(&out[t0 * 3 + q], a);
        }
    } else if (q == 0) {
        // boundary node (~128 total): elements straddle two out rows; per-element
#pragma unroll
        for (int i = 0; i < 8; i++) {
            int f = f0 + 8 * p + i;
            int t = f / NN;
            int nw = f - t * NN;
            float v = s[i];
            atomicAdd(&out[t * 3 + 0], v * Wout[nw]);
            atomicAdd(&out[t * 3 + 1], v * Wout[NN + nw]);
            atomicAdd(&out[t * 3 + 2], v * Wout[2 * NN + nw]);
        }
    }
}

extern "C" void kernel_launch(void* const* d_in, const int* in_sizes, int n_in,
                              void* d_out, int out_size, void* d_ws, size_t ws_size,
                              hipStream_t stream) {
    const float4* x    = (const float4*)d_in[0];  // [N,T]
    const int*    ei   = (const int*)d_in[1];     // [2,E]
    const float*  cw   = (const float*)d_in[2];   // [L,1,1,K]
    const float*  cb   = (const float*)d_in[3];   // [L,1]
    const float*  Wout = (const float*)d_in[4];   // [3,N]
    const float*  bout = (const float*)d_in[5];   // [3]
    float* out = (float*)d_out;                   // [T,3]

    char* ws = (char*)d_ws;
    size_t off = 0;
    auto alloc = [&](size_t bytes) -> void* {
        void* p = ws + off;
        off += (bytes + 255) & ~(size_t)255;
        return p;
    };
    f16x8*        x16     = (f16x8*)alloc((size_t)NN * TT * 2);
    f16x8*        yA      = (f16x8*)alloc((size_t)NN * TT * 2);
    f16x8*        yB      = (f16x8*)alloc((size_t)NN * TT * 2);
    unsigned int* binned  = (unsigned int*)alloc((size_t)NBUCK * BCAP * 4);
    int*          gcursor = (int*)alloc((size_t)NBUCK * 4);
    int*          offsets = (int*)alloc((size_t)(NN + 1) * 4);
    float*        inv_cnt = (float*)alloc((size_t)NN * 4);
    int*          col     = (int*)alloc((size_t)EE * 4);

    // CSR build + cvt + out-bias-init (ws/out are re-poisoned before every call)
    hipMemsetAsync(gcursor, 0, (size_t)NBUCK * 4, stream);
    bin_cvt_kernel<<<BINB + CVTB + 1, 1024, 0, stream>>>(ei, gcursor, binned,
                                                         x, (f16x4*)x16, bout, out);
    bucket_csr_kernel<<<NBUCK, 1024, 0, stream>>>(binned, gcursor, offsets, inv_cnt, col);

    // layers 1-2 (conv commuted past gather; bias/mean folded exactly)
    fused_layer_kernel<<<NN / 4, 256, 0, stream>>>(x16, offsets, col, inv_cnt,
                                                   cw + 0 * KK, cb + 0, yA);
    fused_layer_kernel<<<NN / 4, 256, 0, stream>>>(yA, offsets, col, inv_cnt,
                                                   cw + 1 * KK, cb + 1, yB);
    // layer 3 + output head fused (y3 stays in registers; out pre-seeded with bias)
    layer3_out_kernel<<<NN / 4, 256, 0, stream>>>(yB, offsets, col, inv_cnt,
                                                  cw + 2 * KK, cb + 2, Wout, out);
}

// Round 12
// 356.542 us; speedup vs baseline: 1.9313x; 1.9313x over previous
//
#include <hip/hip_runtime.h>

// Problem constants (match reference)
#define NN 100000
#define TT 128
#define EE 1600000
#define KK 9

// Binned CSR build: 512-node buckets
#define BSH 9
#define BMASK 511
#define NBUCK 196                 // ceil(100000/512)
#define BCAP 10240                // avg 8163/bucket, sigma~90 -> 23 sigma headroom
#define EPB 4096                  // edges per bin block
#define BINB 391                  // ceil(EE/EPB)
#define CVTB 3125                 // NN*TT/4 / 1024

#define NPART 25000               // NN/4 blocks in layer3

typedef _Float16 f16;
typedef __attribute__((ext_vector_type(4))) _Float16 f16x4;
typedef __attribute__((ext_vector_type(8))) _Float16 f16x8;

union HU8 { f16x8 h; int4 i; };

// ---------- fused: bin edges (blocks 0..BINB) + x fp32->fp16 + init out=bias ----------
// Packed edge: (dlocal << 20) | src   (src < 2^17, dlocal < 2^9)
__global__ __launch_bounds__(1024)
void bin_cvt_kernel(const int* __restrict__ ei, int* __restrict__ gcursor,
                    unsigned int* __restrict__ binned,
                    const float4* __restrict__ x, f16x4* __restrict__ x16,
                    const float* __restrict__ bout, float* __restrict__ out) {
    __shared__ int hist[NBUCK];
    __shared__ int gbase[NBUCK];
    int tid = threadIdx.x;

    if (blockIdx.x >= BINB + CVTB) {          // one block: init out with the bias
        if (tid < TT * 3) out[tid] = bout[tid - (tid / 3) * 3];
        return;
    }
    if (blockIdx.x >= BINB) {
        // cvt part: one float4 per thread over N*T/4 (exactly CVTB*1024 elements)
        int i = (blockIdx.x - BINB) * 1024 + tid;
        float4 v = x[i];
        f16x4 o;
        o.x = (f16)v.x; o.y = (f16)v.y; o.z = (f16)v.z; o.w = (f16)v.w;
        x16[i] = o;
        return;
    }

    if (tid < NBUCK) hist[tid] = 0;
    __syncthreads();
    int base = blockIdx.x * EPB;
    unsigned int val[4];
    short bkt[4];
    short rank[4];
#pragma unroll
    for (int k = 0; k < 4; k++) {
        int e = base + k * 1024 + tid;
        bkt[k] = -1;
        if (e < EE) {
            int s = ei[e];            // src
            int d = ei[EE + e];       // dst
            bkt[k] = (short)(d >> BSH);
            val[k] = ((unsigned int)(d & BMASK) << 20) | (unsigned int)s;
            rank[k] = (short)atomicAdd(&hist[bkt[k]], 1);
        }
    }
    __syncthreads();
    if (tid < NBUCK) gbase[tid] = hist[tid] ? atomicAdd(&gcursor[tid], hist[tid]) : 0;
    __syncthreads();
#pragma unroll
    for (int k = 0; k < 4; k++) {
        if (bkt[k] >= 0)
            binned[(size_t)bkt[k] * BCAP + gbase[bkt[k]] + (int)rank[k]] = val[k];
    }
}

// ---------- per-bucket (512 nodes): bucket-base scan + hist + scan + offsets/inv_cnt + place ----------
__global__ __launch_bounds__(1024)
void bucket_csr_kernel(const unsigned int* __restrict__ binned,
                       const int* __restrict__ gcursor,
                       int* __restrict__ offsets,
                       float* __restrict__ inv_cnt,
                       int* __restrict__ col) {
    __shared__ int hist[512];
    __shared__ int cur[512];
    __shared__ int smB[256];
    __shared__ int sc[512];
    int b = blockIdx.x;
    int tid = threadIdx.x;

    // bucket-base scan over all 196 bucket counts (threads 0..255; ~µs)
    if (tid < 256) smB[tid] = (tid < NBUCK) ? gcursor[tid] : 0;
    __syncthreads();
    for (int off = 1; off < 256; off <<= 1) {
        int v = 0;
        if (tid < 256 && tid >= off) v = smB[tid - off];
        __syncthreads();
        if (tid < 256) smB[tid] += v;
        __syncthreads();
    }
    int bucket_base = (b == 0) ? 0 : smB[b - 1];
    if (b == 0 && tid == 0) offsets[NN] = EE;

    int cnt = gcursor[b];
    const unsigned int* ePtr = binned + (size_t)b * BCAP;
    if (tid < 512) hist[tid] = 0;
    __syncthreads();
    for (int j = tid; j < cnt; j += 1024)          // ~8 iterations
        atomicAdd(&hist[ePtr[j] >> 20], 1);
    __syncthreads();
    int d = (tid < 512) ? hist[tid] : 0;
    if (tid < 512) sc[tid] = d;
    __syncthreads();
    for (int off = 1; off < 512; off <<= 1) {      // inclusive scan of 512 degrees
        int v = 0;
        if (tid < 512 && tid >= off) v = sc[tid - off];
        __syncthreads();
        if (tid < 512) sc[tid] += v;
        __syncthreads();
    }
    if (tid < 512) {
        int node = (b << BSH) + tid;
        int pos = bucket_base + sc[tid] - d;       // exclusive prefix
        if (node < NN) {
            offsets[node] = pos;
            inv_cnt[node] = 1.0f / (1.0f + (float)d);
            cur[tid] = pos;
        }
    }
    __syncthreads();
    // place: all writes land in this bucket's contiguous col window (~32 KB, L2-resident)
    for (int j = tid; j < cnt; j += 1024) {        // ~8 iterations
        unsigned int v = ePtr[j];
        int pos = atomicAdd(&cur[v >> 20], 1);
        col[pos] = (int)(v & 0xFFFFF);
    }
}

// ---------- shared gather+conv body (one wave per node) ----------
// p = lane&15 owns t = {8p..8p+7} (f16x8, 16B); quarter-groups q process 4 edges
// per 1 KiB load; packed-fp16 accumulate; xor-16/32 combine; fp32 conv epilogue.
// Result: s[0..7] = relu(conv(...)*ic + b) for t = 8p..8p+7, valid on ALL lanes.
__device__ __forceinline__ void gather_conv_node(
    const f16x8* __restrict__ xin, const int* __restrict__ offsets,
    const int* __restrict__ col, const float* __restrict__ inv_cnt,
    const float* wr, float bb, int node, int lane, int q, int p, float* s)
{
    int lo = offsets[node], hi = offsets[node + 1];
    int cnt = hi - lo;
    int my_col = (lane < cnt) ? col[lo + lane] : 0;
    int jn = cnt < 64 ? cnt : 64;

    const f16 z = (f16)0;
    f16x8 acc0 = {z, z, z, z, z, z, z, z};
    f16x8 acc1 = {z, z, z, z, z, z, z, z};

    int j = 0;
    for (; j + 7 < jn; j += 8) {               // 8 edges / iter, 2 loads in flight
        int c0 = __shfl(my_col, j + q);
        int c1 = __shfl(my_col, j + 4 + q);
        f16x8 v0 = xin[(c0 << 4) | p];
        f16x8 v1 = xin[(c1 << 4) | p];
        acc0 += v0;
        acc1 += v1;
    }
    for (; j + 3 < jn; j += 4) {               // 4 edges
        int c = __shfl(my_col, j + q);
        acc0 += xin[(c << 4) | p];
    }
    if (j < jn) {                              // tail 1..3 edges
        int rem = jn - j;
        int c = __shfl(my_col, j + (q < rem ? q : 0));
        f16x8 v = xin[(c << 4) | p];
        if (q < rem) acc1 += v;
    }
    for (int k = 64; k < cnt; k++) {           // degree > 64 (effectively never)
        int c = col[lo + k];
        f16x8 v = xin[(c << 4) | p];
        if (q == 0) acc0 += v;
    }
    acc0 += acc1;

    {   // combine the 4 quarter-groups: xor-16 then xor-32
        HU8 u; u.h = acc0;
        int4 o;
        o.x = __shfl_xor(u.i.x, 16); o.y = __shfl_xor(u.i.y, 16);
        o.z = __shfl_xor(u.i.z, 16); o.w = __shfl_xor(u.i.w, 16);
        HU8 w2; w2.i = o;
        acc0 += w2.h;
        u.h = acc0;
        o.x = __shfl_xor(u.i.x, 32); o.y = __shfl_xor(u.i.y, 32);
        o.z = __shfl_xor(u.i.z, 32); o.w = __shfl_xor(u.i.w, 32);
        w2.i = o;
        acc0 += w2.h;
    }

    // fp32 epilogue: + self row, conv K=9, mean, bias, relu
    f16x8 sv = xin[(node << 4) | p];
    float A[16];
    A[4]  = (float)acc0[0] + (float)sv[0];
    A[5]  = (float)acc0[1] + (float)sv[1];
    A[6]  = (float)acc0[2] + (float)sv[2];
    A[7]  = (float)acc0[3] + (float)sv[3];
    A[8]  = (float)acc0[4] + (float)sv[4];
    A[9]  = (float)acc0[5] + (float)sv[5];
    A[10] = (float)acc0[6] + (float)sv[6];
    A[11] = (float)acc0[7] + (float)sv[7];
#pragma unroll
    for (int i = 0; i < 4; i++) {
        A[i]      = __shfl_up(A[8 + i], 1, 16);    // prev lane's a[4..7]
        A[12 + i] = __shfl_down(A[4 + i], 1, 16);  // next lane's a[0..3]
    }
    if (p == 0)  { A[0] = 0.0f; A[1] = 0.0f; A[2] = 0.0f; A[3] = 0.0f; }
    if (p == 15) { A[12] = 0.0f; A[13] = 0.0f; A[14] = 0.0f; A[15] = 0.0f; }

    float ic = inv_cnt[node];
#pragma unroll
    for (int i = 0; i < 8; i++) {
        float t = 0.0f;
#pragma unroll
        for (int k = 0; k < KK; k++) t += wr[k] * A[i + k];
        s[i] = fmaxf(t * ic + bb, 0.0f);
    }
}

// ---------- layers 1-2: store y as f16x8 (one wave per node, one-shot blocks) ----------
__global__ void fused_layer_kernel(const f16x8* __restrict__ xin,
                                   const int* __restrict__ offsets,
                                   const int* __restrict__ col,
                                   const float* __restrict__ inv_cnt,
                                   const float* __restrict__ w9,
                                   const float* __restrict__ bptr,
                                   f16x8* __restrict__ yout) {
    int tid = threadIdx.x;
    int lane = tid & 63;
    int q = lane >> 4;
    int p = lane & 15;
    int node = blockIdx.x * 4 + (tid >> 6);
    float wr[KK];
#pragma unroll
    for (int k = 0; k < KK; k++) wr[k] = w9[k];
    float s[8];
    gather_conv_node(xin, offsets, col, inv_cnt, wr, bptr[0], node, lane, q, p, s);
    if (q == 0) {
        f16x8 o;
#pragma unroll
        for (int i = 0; i < 8; i++) o[i] = (f16)s[i];
        yout[(node << 4) | p] = o;
    }
}

// ---------- layer 3 fused with output head, partial-sum version ----------
// Flat view: node n's row occupies flat f = n*128..n*128+127 -> out row t = f/NN.
// Fast path (block's 4 node-rows all in one out row t0): per-wave channel dot,
// 12 LDS atomics, block writes 3 PLAIN stores to partial[blk*3..]. No hot atomics.
// Slow path (~250 blocks/nodes near boundaries): direct global atomics (rare).
__global__ void layer3_out_kernel(const f16x8* __restrict__ xin,
                                  const int* __restrict__ offsets,
                                  const int* __restrict__ col,
                                  const float* __restrict__ inv_cnt,
                                  const float* __restrict__ w9,
                                  const float* __restrict__ bptr,
                                  const float* __restrict__ Wout,
                                  float* __restrict__ out,
                                  float* __restrict__ partial) {
    __shared__ float bacc[3];
    int tid = threadIdx.x;
    if (tid < 3) bacc[tid] = 0.0f;
    __syncthreads();

    int lane = tid & 63;
    int q = lane >> 4;
    int p = lane & 15;
    int blk = blockIdx.x;
    int node = blk * 4 + (tid >> 6);
    float wr[KK];
#pragma unroll
    for (int k = 0; k < KK; k++) wr[k] = w9[k];
    float s[8];
    gather_conv_node(xin, offsets, col, inv_cnt, wr, bptr[0], node, lane, q, p, s);

    int f_first = blk * 4 * TT;
    int f_last = f_first + 4 * TT - 1;
    bool block_same_t = (f_first / NN) == (f_last / NN);

    int f0 = node * TT;
    int t0 = f0 / NN;
    int r0 = f0 - t0 * NN;

    if (block_same_t) {
        // fast path: channel q partial dot over this node's 128-elem Wout run
        if (q < 3) {
            const float4* Wrow = (const float4*)(Wout + q * NN + r0 + 8 * p);
            float4 w0 = Wrow[0];
            float4 w1 = Wrow[1];
            float a = s[0] * w0.x + s[1] * w0.y + s[2] * w0.z + s[3] * w0.w
                    + s[4] * w1.x + s[5] * w1.y + s[6] * w1.z + s[7] * w1.w;
            for (int o = 8; o > 0; o >>= 1) a += __shfl_down(a, o, 16);
            if (p == 0) atomicAdd(&bacc[q], a);   // LDS atomic: 12 per block
        }
        __syncthreads();
        if (tid < 3) partial[blk * 3 + tid] = bacc[tid];
    } else {
        // slow path: ~127 straddling blocks; per-node, even per-element if needed
        if (r0 + TT <= NN) {
            if (q < 3) {
                const float4* Wrow = (const float4*)(Wout + q * NN + r0 + 8 * p);
                float4 w0 = Wrow[0];
                float4 w1 = Wrow[1];
                float a = s[0] * w0.x + s[1] * w0.y + s[2] * w0.z + s[3] * w0.w
                        + s[4] * w1.x + s[5] * w1.y + s[6] * w1.z + s[7] * w1.w;
                for (int o = 8; o > 0; o >>= 1) a += __shfl_down(a, o, 16);
                if (p == 0) atomicAdd(&out[t0 * 3 + q], a);
            }
        } else if (q == 0) {
            // node's row itself straddles two out rows (~128 nodes total)
#pragma unroll
            for (int i = 0; i < 8; i++) {
                int f = f0 + 8 * p + i;
                int t = f / NN;
                int nw = f - t * NN;
                float v = s[i];
                atomicAdd(&out[t * 3 + 0], v * Wout[nw]);
                atomicAdd(&out[t * 3 + 1], v * Wout[NN + nw]);
                atomicAdd(&out[t * 3 + 2], v * Wout[2 * NN + nw]);
            }
        }
        __syncthreads();
        if (tid < 3) partial[blk * 3 + tid] = 0.0f;
    }
}

// ---------- reduce partials: one block per out row t ----------
__global__ void out_reduce_kernel(const float* __restrict__ partial,
                                  float* __restrict__ out) {
    __shared__ float red[4][3];
    int t = blockIdx.x;
    int tid = threadIdx.x;
    // blocks b with t0(b) = (512*b)/NN == t:
    int lo = (NN * t + 511) >> 9;          // ceil(NN*t/512)
    int hi = (NN * (t + 1) + 511) >> 9;
    if (hi > NPART) hi = NPART;
    float a0 = 0.0f, a1 = 0.0f, a2 = 0.0f;
    for (int b = lo + tid; b < hi; b += 256) {
        a0 += partial[b * 3 + 0];
        a1 += partial[b * 3 + 1];
        a2 += partial[b * 3 + 2];
    }
    for (int o = 32; o > 0; o >>= 1) {
        a0 += __shfl_down(a0, o);
        a1 += __shfl_down(a1, o);
        a2 += __shfl_down(a2, o);
    }
    int wave = tid >> 6;
    if ((tid & 63) == 0) {
        red[wave][0] = a0;
        red[wave][1] = a1;
        red[wave][2] = a2;
    }
    __syncthreads();
    if (tid == 0) {
        // out already holds bias + slow-path contributions (stream-ordered)
        atomicAdd(&out[t * 3 + 0], red[0][0] + red[1][0] + red[2][0] + red[3][0]);
        atomicAdd(&out[t * 3 + 1], red[0][1] + red[1][1] + red[2][1] + red[3][1]);
        atomicAdd(&out[t * 3 + 2], red[0][2] + red[1][2] + red[2][2] + red[3][2]);
    }
}

extern "C" void kernel_launch(void* const* d_in, const int* in_sizes, int n_in,
                              void* d_out, int out_size, void* d_ws, size_t ws_size,
                              hipStream_t stream) {
    const float4* x    = (const float4*)d_in[0];  // [N,T]
    const int*    ei   = (const int*)d_in[1];     // [2,E]
    const float*  cw   = (const float*)d_in[2];   // [L,1,1,K]
    const float*  cb   = (const float*)d_in[3];   // [L,1]
    const float*  Wout = (const float*)d_in[4];   // [3,N]
    const float*  bout = (const float*)d_in[5];   // [3]
    float* out = (float*)d_out;                   // [T,3]

    char* ws = (char*)d_ws;
    size_t off = 0;
    auto alloc = [&](size_t bytes) -> void* {
        void* p = ws + off;
        off += (bytes + 255) & ~(size_t)255;
        return p;
    };
    f16x8*        x16     = (f16x8*)alloc((size_t)NN * TT * 2);
    f16x8*        yA      = (f16x8*)alloc((size_t)NN * TT * 2);
    f16x8*        yB      = (f16x8*)alloc((size_t)NN * TT * 2);
    unsigned int* binned  = (unsigned int*)alloc((size_t)NBUCK * BCAP * 4);
    int*          gcursor = (int*)alloc((size_t)NBUCK * 4);
    int*          offsets = (int*)alloc((size_t)(NN + 1) * 4);
    float*        inv_cnt = (float*)alloc((size_t)NN * 4);
    int*          col     = (int*)alloc((size_t)EE * 4);
    float*        partial = (float*)alloc((size_t)NPART * 3 * 4);

    // CSR build + cvt + out-bias-init (ws/out are re-poisoned before every call)
    hipMemsetAsync(gcursor, 0, (size_t)NBUCK * 4, stream);
    bin_cvt_kernel<<<BINB + CVTB + 1, 1024, 0, stream>>>(ei, gcursor, binned,
                                                         x, (f16x4*)x16, bout, out);
    bucket_csr_kernel<<<NBUCK, 1024, 0, stream>>>(binned, gcursor, offsets, inv_cnt, col);

    // layers 1-2 (conv commuted past gather; bias/mean folded exactly)
    fused_layer_kernel<<<NN / 4, 256, 0, stream>>>(x16, offsets, col, inv_cnt,
                                                   cw + 0 * KK, cb + 0, yA);
    fused_layer_kernel<<<NN / 4, 256, 0, stream>>>(yA, offsets, col, inv_cnt,
                                                   cw + 1 * KK, cb + 1, yB);
    // layer 3 + output head fused: partial sums via plain stores, no hot atomics
    layer3_out_kernel<<<NPART, 256, 0, stream>>>(yB, offsets, col, inv_cnt,
                                                 cw + 2 * KK, cb + 2, Wout, out, partial);
    out_reduce_kernel<<<TT, 256, 0, stream>>>(partial, out);
}

// Round 13
// 352.471 us; speedup vs baseline: 1.9536x; 1.0116x over previous
//
#include <hip/hip_runtime.h>

// Problem constants (match reference)
#define NN 100000
#define TT 128
#define EE 1600000
#define KK 9

// Binned CSR build: 512-node buckets
#define BSH 9
#define BMASK 511
#define NBUCK 196                 // ceil(100000/512)
#define BCAP 10240                // avg 8163/bucket, sigma~90 -> 23 sigma headroom
#define EPB 4096                  // edges per bin block
#define BINB 391                  // ceil(EE/EPB)
#define CVTB 3125                 // NN*TT/4 / 1024

// Output head: 64 n-slices x 16 t-groups
#define OSLICE 1568               // even; 64*1568 >= NN
#define ONS 64
#define OTG 16

typedef _Float16 f16;
typedef __attribute__((ext_vector_type(2))) _Float16 f16x2;
typedef __attribute__((ext_vector_type(4))) _Float16 f16x4;
typedef __attribute__((ext_vector_type(8))) _Float16 f16x8;

union HU8 { f16x8 h; int4 i; };

// ---------- fused: bin edges (blocks 0..BINB) + x fp32->fp16 ----------
// Packed edge: (dlocal << 20) | src   (src < 2^17, dlocal < 2^9)
__global__ __launch_bounds__(1024)
void bin_cvt_kernel(const int* __restrict__ ei, int* __restrict__ gcursor,
                    unsigned int* __restrict__ binned,
                    const float4* __restrict__ x, f16x4* __restrict__ x16) {
    __shared__ int hist[NBUCK];
    __shared__ int gbase[NBUCK];
    int tid = threadIdx.x;

    if (blockIdx.x >= BINB) {
        // cvt part: one float4 per thread over N*T/4 (exactly CVTB*1024 elements)
        int i = (blockIdx.x - BINB) * 1024 + tid;
        float4 v = x[i];
        f16x4 o;
        o.x = (f16)v.x; o.y = (f16)v.y; o.z = (f16)v.z; o.w = (f16)v.w;
        x16[i] = o;
        return;
    }

    if (tid < NBUCK) hist[tid] = 0;
    __syncthreads();
    int base = blockIdx.x * EPB;
    unsigned int val[4];
    short bkt[4];
    short rank[4];
#pragma unroll
    for (int k = 0; k < 4; k++) {
        int e = base + k * 1024 + tid;
        bkt[k] = -1;
        if (e < EE) {
            int s = ei[e];            // src
            int d = ei[EE + e];       // dst
            bkt[k] = (short)(d >> BSH);
            val[k] = ((unsigned int)(d & BMASK) << 20) | (unsigned int)s;
            rank[k] = (short)atomicAdd(&hist[bkt[k]], 1);
        }
    }
    __syncthreads();
    if (tid < NBUCK) gbase[tid] = hist[tid] ? atomicAdd(&gcursor[tid], hist[tid]) : 0;
    __syncthreads();
#pragma unroll
    for (int k = 0; k < 4; k++) {
        if (bkt[k] >= 0)
            binned[(size_t)bkt[k] * BCAP + gbase[bkt[k]] + (int)rank[k]] = val[k];
    }
}

// ---------- per-bucket (512 nodes): bucket-base scan + hist + scan + offsets/inv_cnt + place ----------
__global__ __launch_bounds__(1024)
void bucket_csr_kernel(const unsigned int* __restrict__ binned,
                       const int* __restrict__ gcursor,
                       int* __restrict__ offsets,
                       float* __restrict__ inv_cnt,
                       int* __restrict__ col) {
    __shared__ int hist[512];
    __shared__ int cur[512];
    __shared__ int smB[256];
    __shared__ int sc[512];
    int b = blockIdx.x;
    int tid = threadIdx.x;

    // bucket-base scan over all 196 bucket counts (threads 0..255; ~µs)
    if (tid < 256) smB[tid] = (tid < NBUCK) ? gcursor[tid] : 0;
    __syncthreads();
    for (int off = 1; off < 256; off <<= 1) {
        int v = 0;
        if (tid < 256 && tid >= off) v = smB[tid - off];
        __syncthreads();
        if (tid < 256) smB[tid] += v;
        __syncthreads();
    }
    int bucket_base = (b == 0) ? 0 : smB[b - 1];
    if (b == 0 && tid == 0) offsets[NN] = EE;

    int cnt = gcursor[b];
    const unsigned int* ePtr = binned + (size_t)b * BCAP;
    if (tid < 512) hist[tid] = 0;
    __syncthreads();
    for (int j = tid; j < cnt; j += 1024)          // ~8 iterations
        atomicAdd(&hist[ePtr[j] >> 20], 1);
    __syncthreads();
    int d = (tid < 512) ? hist[tid] : 0;
    if (tid < 512) sc[tid] = d;
    __syncthreads();
    for (int off = 1; off < 512; off <<= 1) {      // inclusive scan of 512 degrees
        int v = 0;
        if (tid < 512 && tid >= off) v = sc[tid - off];
        __syncthreads();
        if (tid < 512) sc[tid] += v;
        __syncthreads();
    }
    if (tid < 512) {
        int node = (b << BSH) + tid;
        int pos = bucket_base + sc[tid] - d;       // exclusive prefix
        if (node < NN) {
            offsets[node] = pos;
            inv_cnt[node] = 1.0f / (1.0f + (float)d);
            cur[tid] = pos;
        }
    }
    __syncthreads();
    // place: all writes land in this bucket's contiguous col window (~32 KB, L2-resident)
    for (int j = tid; j < cnt; j += 1024) {        // ~8 iterations
        unsigned int v = ePtr[j];
        int pos = atomicAdd(&cur[v >> 20], 1);
        col[pos] = (int)(v & 0xFFFFF);
    }
}

// ---------- shared gather+conv body (one wave per node) ----------
// p = lane&15 owns t = {8p..8p+7} (f16x8, 16B); quarter-groups q process 4 edges
// per 1 KiB load; packed-fp16 accumulate; xor-16/32 combine; fp32 conv epilogue.
__device__ __forceinline__ void gather_conv_node(
    const f16x8* __restrict__ xin, const int* __restrict__ offsets,
    const int* __restrict__ col, const float* __restrict__ inv_cnt,
    const float* wr, float bb, int node, int lane, int q, int p, float* s)
{
    int lo = offsets[node], hi = offsets[node + 1];
    int cnt = hi - lo;
    int my_col = (lane < cnt) ? col[lo + lane] : 0;
    int jn = cnt < 64 ? cnt : 64;

    const f16 z = (f16)0;
    f16x8 acc0 = {z, z, z, z, z, z, z, z};
    f16x8 acc1 = {z, z, z, z, z, z, z, z};

    int j = 0;
    for (; j + 7 < jn; j += 8) {               // 8 edges / iter, 2 loads in flight
        int c0 = __shfl(my_col, j + q);
        int c1 = __shfl(my_col, j + 4 + q);
        f16x8 v0 = xin[(c0 << 4) | p];
        f16x8 v1 = xin[(c1 << 4) | p];
        acc0 += v0;
        acc1 += v1;
    }
    for (; j + 3 < jn; j += 4) {               // 4 edges
        int c = __shfl(my_col, j + q);
        acc0 += xin[(c << 4) | p];
    }
    if (j < jn) {                              // tail 1..3 edges
        int rem = jn - j;
        int c = __shfl(my_col, j + (q < rem ? q : 0));
        f16x8 v = xin[(c << 4) | p];
        if (q < rem) acc1 += v;
    }
    for (int k = 64; k < cnt; k++) {           // degree > 64 (effectively never)
        int c = col[lo + k];
        f16x8 v = xin[(c << 4) | p];
        if (q == 0) acc0 += v;
    }
    acc0 += acc1;

    {   // combine the 4 quarter-groups: xor-16 then xor-32
        HU8 u; u.h = acc0;
        int4 o;
        o.x = __shfl_xor(u.i.x, 16); o.y = __shfl_xor(u.i.y, 16);
        o.z = __shfl_xor(u.i.z, 16); o.w = __shfl_xor(u.i.w, 16);
        HU8 w2; w2.i = o;
        acc0 += w2.h;
        u.h = acc0;
        o.x = __shfl_xor(u.i.x, 32); o.y = __shfl_xor(u.i.y, 32);
        o.z = __shfl_xor(u.i.z, 32); o.w = __shfl_xor(u.i.w, 32);
        w2.i = o;
        acc0 += w2.h;
    }

    // fp32 epilogue: + self row, conv K=9, mean, bias, relu
    f16x8 sv = xin[(node << 4) | p];
    float A[16];
    A[4]  = (float)acc0[0] + (float)sv[0];
    A[5]  = (float)acc0[1] + (float)sv[1];
    A[6]  = (float)acc0[2] + (float)sv[2];
    A[7]  = (float)acc0[3] + (float)sv[3];
    A[8]  = (float)acc0[4] + (float)sv[4];
    A[9]  = (float)acc0[5] + (float)sv[5];
    A[10] = (float)acc0[6] + (float)sv[6];
    A[11] = (float)acc0[7] + (float)sv[7];
#pragma unroll
    for (int i = 0; i < 4; i++) {
        A[i]      = __shfl_up(A[8 + i], 1, 16);    // prev lane's a[4..7]
        A[12 + i] = __shfl_down(A[4 + i], 1, 16);  // next lane's a[0..3]
    }
    if (p == 0)  { A[0] = 0.0f; A[1] = 0.0f; A[2] = 0.0f; A[3] = 0.0f; }
    if (p == 15) { A[12] = 0.0f; A[13] = 0.0f; A[14] = 0.0f; A[15] = 0.0f; }

    float ic = inv_cnt[node];
#pragma unroll
    for (int i = 0; i < 8; i++) {
        float t = 0.0f;
#pragma unroll
        for (int k = 0; k < KK; k++) t += wr[k] * A[i + k];
        s[i] = fmaxf(t * ic + bb, 0.0f);
    }
}

// ---------- layers: 1024-thr blocks, 16 nodes/block (grid 6250 -> 4x less ramp) ----------
__global__ __launch_bounds__(1024)
void fused_layer_kernel(const f16x8* __restrict__ xin,
                        const int* __restrict__ offsets,
                        const int* __restrict__ col,
                        const float* __restrict__ inv_cnt,
                        const float* __restrict__ w9,
                        const float* __restrict__ bptr,
                        f16x8* __restrict__ yout) {
    int tid = threadIdx.x;
    int lane = tid & 63;
    int q = lane >> 4;
    int p = lane & 15;
    int node = blockIdx.x * 16 + (tid >> 6);
    float wr[KK];
#pragma unroll
    for (int k = 0; k < KK; k++) wr[k] = w9[k];
    float s[8];
    gather_conv_node(xin, offsets, col, inv_cnt, wr, bptr[0], node, lane, q, p, s);
    if (q == 0) {
        f16x8 o;
#pragma unroll
        for (int i = 0; i < 8; i++) o[i] = (f16)s[i];
        yout[(node << 4) | p] = o;
    }
}

// ---------- output head, stage 1: partial[t][sp] = dot(y3flat[t, n-slice], Wout[, n-slice]) ----------
// Block (sp, tg) owns n in [sp*OSLICE, ...+OSLICE) and t in [tg*8, tg*8+8):
// Wout slice re-read 8x from L2 (9.6 MB total, vs 153 MB in the old t-major grid);
// y3 read exactly once; partials via PLAIN stores (no atomics anywhere).
__global__ void out_partial_kernel(const f16* __restrict__ y3,
                                   const float* __restrict__ Wout,
                                   float* __restrict__ partial) {
    __shared__ float red[4][3];
    int sp = blockIdx.x;
    int tg = blockIdx.y;
    int tid = threadIdx.x;
    int lane = tid & 63;
    int wave = tid >> 6;
    int n0 = sp * OSLICE;
    int n1 = n0 + OSLICE;
    if (n1 > NN) n1 = NN;
    for (int t = tg * 8; t < tg * 8 + 8; t++) {
        const f16* yrow = y3 + (size_t)t * NN;
        float a0 = 0.0f, a1 = 0.0f, a2 = 0.0f;
        for (int n = n0 + tid * 2; n < n1; n += 512) {
            f16x2 v = *(const f16x2*)(yrow + n);
            float vx = (float)v.x, vy = (float)v.y;
            float2 wA = *(const float2*)(Wout + n);
            float2 wB = *(const float2*)(Wout + NN + n);
            float2 wC = *(const float2*)(Wout + 2 * NN + n);
            a0 += vx * wA.x + vy * wA.y;
            a1 += vx * wB.x + vy * wB.y;
            a2 += vx * wC.x + vy * wC.y;
        }
        for (int o = 32; o > 0; o >>= 1) {
            a0 += __shfl_down(a0, o);
            a1 += __shfl_down(a1, o);
            a2 += __shfl_down(a2, o);
        }
        if (lane == 0) {
            red[wave][0] = a0;
            red[wave][1] = a1;
            red[wave][2] = a2;
        }
        __syncthreads();
        if (tid == 0) {
            int idx = (t * ONS + sp) * 3;
            partial[idx + 0] = red[0][0] + red[1][0] + red[2][0] + red[3][0];
            partial[idx + 1] = red[0][1] + red[1][1] + red[2][1] + red[3][1];
            partial[idx + 2] = red[0][2] + red[1][2] + red[2][2] + red[3][2];
        }
        __syncthreads();
    }
}

// ---------- output head, stage 2: out[t][c] = bias[c] + sum_sp partial[t][sp][c] ----------
// One wave per t; plain stores; sole writer of out.
__global__ void out_reduce_kernel(const float* __restrict__ partial,
                                  const float* __restrict__ bout,
                                  float* __restrict__ out) {
    int t = blockIdx.x;
    int l = threadIdx.x;    // 64
    int idx = (t * ONS + l) * 3;
    float a0 = partial[idx + 0];
    float a1 = partial[idx + 1];
    float a2 = partial[idx + 2];
    for (int o = 32; o > 0; o >>= 1) {
        a0 += __shfl_down(a0, o);
        a1 += __shfl_down(a1, o);
        a2 += __shfl_down(a2, o);
    }
    if (l == 0) {
        out[t * 3 + 0] = bout[0] + a0;
        out[t * 3 + 1] = bout[1] + a1;
        out[t * 3 + 2] = bout[2] + a2;
    }
}

extern "C" void kernel_launch(void* const* d_in, const int* in_sizes, int n_in,
                              void* d_out, int out_size, void* d_ws, size_t ws_size,
                              hipStream_t stream) {
    const float4* x    = (const float4*)d_in[0];  // [N,T]
    const int*    ei   = (const int*)d_in[1];     // [2,E]
    const float*  cw   = (const float*)d_in[2];   // [L,1,1,K]
    const float*  cb   = (const float*)d_in[3];   // [L,1]
    const float*  Wout = (const float*)d_in[4];   // [3,N]
    const float*  bout = (const float*)d_in[5];   // [3]
    float* out = (float*)d_out;                   // [T,3]

    char* ws = (char*)d_ws;
    size_t off = 0;
    auto alloc = [&](size_t bytes) -> void* {
        void* p = ws + off;
        off += (bytes + 255) & ~(size_t)255;
        return p;
    };
    f16x8*        x16     = (f16x8*)alloc((size_t)NN * TT * 2);
    f16x8*        yA      = (f16x8*)alloc((size_t)NN * TT * 2);
    f16x8*        yB      = (f16x8*)alloc((size_t)NN * TT * 2);
    unsigned int* binned  = (unsigned int*)alloc((size_t)NBUCK * BCAP * 4);
    int*          gcursor = (int*)alloc((size_t)NBUCK * 4);
    int*          offsets = (int*)alloc((size_t)(NN + 1) * 4);
    float*        inv_cnt = (float*)alloc((size_t)NN * 4);
    int*          col     = (int*)alloc((size_t)EE * 4);
    float*        partial = (float*)alloc((size_t)TT * ONS * 3 * 4);

    // CSR build + cvt (ws/out are re-poisoned before every call)
    hipMemsetAsync(gcursor, 0, (size_t)NBUCK * 4, stream);
    bin_cvt_kernel<<<BINB + CVTB, 1024, 0, stream>>>(ei, gcursor, binned, x, (f16x4*)x16);
    bucket_csr_kernel<<<NBUCK, 1024, 0, stream>>>(binned, gcursor, offsets, inv_cnt, col);

    // 3 fused layers (conv commuted past gather; bias/mean folded exactly)
    fused_layer_kernel<<<NN / 16, 1024, 0, stream>>>(x16, offsets, col, inv_cnt,
                                                     cw + 0 * KK, cb + 0, yA);
    fused_layer_kernel<<<NN / 16, 1024, 0, stream>>>(yA, offsets, col, inv_cnt,
                                                     cw + 1 * KK, cb + 1, yB);
    fused_layer_kernel<<<NN / 16, 1024, 0, stream>>>(yB, offsets, col, inv_cnt,
                                                     cw + 2 * KK, cb + 2, yA);

    // output head: y3/Wout read ~once; partials via plain stores, then tiny reduce
    out_partial_kernel<<<dim3(ONS, OTG), 256, 0, stream>>>((const f16*)yA, Wout, partial);
    out_reduce_kernel<<<TT, 64, 0, stream>>>(partial, bout, out);
}

// Round 14
// 344.847 us; speedup vs baseline: 1.9968x; 1.0221x over previous
//
#include <hip/hip_runtime.h>

// Problem constants (match reference)
#define NN 100000
#define TT 128
#define EE 1600000
#define KK 9

// Binned CSR build: 512-node buckets
#define BSH 9
#define BMASK 511
#define NBUCK 196                 // ceil(100000/512)
#define BCAP 10240                // avg 8163/bucket, sigma~90 -> 23 sigma headroom
#define EPB 4096                  // edges per bin block
#define BINB 391                  // ceil(EE/EPB)
#define CVTB 3125                 // NN*TT/4 / 1024
#define NCHUNK 8                  // chunks per bucket in the place phase

// Output head: 64 n-slices x 16 t-groups
#define OSLICE 1568               // 64*1568 >= NN
#define ONS 64
#define OTG 16

typedef _Float16 f16;
typedef __attribute__((ext_vector_type(2))) _Float16 f16x2;
typedef __attribute__((ext_vector_type(4))) _Float16 f16x4;
typedef __attribute__((ext_vector_type(8))) _Float16 f16x8;

union HU8 { f16x8 h; int4 i; };

// ---------- fused: bin edges (blocks 0..BINB) + x fp32->fp16 ----------
// Packed edge: (dlocal << 20) | src   (src < 2^17, dlocal < 2^9)
__global__ __launch_bounds__(1024)
void bin_cvt_kernel(const int* __restrict__ ei, int* __restrict__ gcursor,
                    unsigned int* __restrict__ binned,
                    const float4* __restrict__ x, f16x4* __restrict__ x16) {
    __shared__ int hist[NBUCK];
    __shared__ int gbase[NBUCK];
    int tid = threadIdx.x;

    if (blockIdx.x >= BINB) {
        // cvt part: one float4 per thread over N*T/4 (exactly CVTB*1024 elements)
        int i = (blockIdx.x - BINB) * 1024 + tid;
        float4 v = x[i];
        f16x4 o;
        o.x = (f16)v.x; o.y = (f16)v.y; o.z = (f16)v.z; o.w = (f16)v.w;
        x16[i] = o;
        return;
    }

    if (tid < NBUCK) hist[tid] = 0;
    __syncthreads();
    int base = blockIdx.x * EPB;
    unsigned int val[4];
    short bkt[4];
    short rank[4];
#pragma unroll
    for (int k = 0; k < 4; k++) {
        int e = base + k * 1024 + tid;
        bkt[k] = -1;
        if (e < EE) {
            int s = ei[e];            // src
            int d = ei[EE + e];       // dst
            bkt[k] = (short)(d >> BSH);
            val[k] = ((unsigned int)(d & BMASK) << 20) | (unsigned int)s;
            rank[k] = (short)atomicAdd(&hist[bkt[k]], 1);
        }
    }
    __syncthreads();
    if (tid < NBUCK) gbase[tid] = hist[tid] ? atomicAdd(&gcursor[tid], hist[tid]) : 0;
    __syncthreads();
#pragma unroll
    for (int k = 0; k < 4; k++) {
        if (bkt[k] >= 0)
            binned[(size_t)bkt[k] * BCAP + gbase[bkt[k]] + (int)rank[k]] = val[k];
    }
}

// ---------- build K1: per-(bucket,chunk) 512-bin histogram -> global chunkhist ----------
__global__ void chunk_hist_kernel(const unsigned int* __restrict__ binned,
                                  const int* __restrict__ gcursor,
                                  int* __restrict__ chunkhist) {
    __shared__ int hist[512];
    int b = blockIdx.x >> 3;
    int c = blockIdx.x & 7;
    int tid = threadIdx.x;
    hist[tid] = 0;
    hist[tid + 256] = 0;
    __syncthreads();
    int cnt = gcursor[b];
    int cs = (cnt + NCHUNK - 1) >> 3;
    int lo = c * cs;
    int hi = lo + cs; if (hi > cnt) hi = cnt;
    const unsigned int* ePtr = binned + (size_t)b * BCAP;
    for (int j = lo + tid; j < hi; j += 256)
        atomicAdd(&hist[ePtr[j] >> 20], 1);
    __syncthreads();
    int o = blockIdx.x * 512;
    chunkhist[o + tid] = hist[tid];
    chunkhist[o + tid + 256] = hist[tid + 256];
}

// ---------- build K2: offsets/inv_cnt (chunk 0) + place own chunk ----------
__global__ void bucket_place_kernel(const unsigned int* __restrict__ binned,
                                    const int* __restrict__ gcursor,
                                    const int* __restrict__ chunkhist,
                                    int* __restrict__ offsets,
                                    float* __restrict__ inv_cnt,
                                    int* __restrict__ col) {
    __shared__ int smB[256];
    __shared__ int sm[256];
    __shared__ int cur[512];
    int b = blockIdx.x >> 3;
    int c = blockIdx.x & 7;
    int tid = threadIdx.x;

    // bucket-base scan over all 196 bucket counts (each block redoes it; cheap)
    smB[tid] = (tid < NBUCK) ? gcursor[tid] : 0;
    __syncthreads();
    for (int off = 1; off < 256; off <<= 1) {
        int v = (tid >= off) ? smB[tid - off] : 0;
        __syncthreads();
        smB[tid] += v;
        __syncthreads();
    }
    int bucket_base = (b == 0) ? 0 : smB[b - 1];
    if (blockIdx.x == 0 && tid == 0) offsets[NN] = EE;

    // totals + my-chunk-prefix for my two nodes (n0 = 2*tid, n1 = 2*tid+1)
    int n0 = 2 * tid, n1 = n0 + 1;
    int tot0 = 0, tot1 = 0, pre0 = 0, pre1 = 0;
#pragma unroll
    for (int cc = 0; cc < NCHUNK; cc++) {
        int o = ((b << 3) | cc) * 512;
        int h0 = chunkhist[o + n0];
        int h1 = chunkhist[o + n1];
        tot0 += h0; tot1 += h1;
        if (cc < c) { pre0 += h0; pre1 += h1; }
    }
    sm[tid] = tot0 + tot1;
    __syncthreads();
    for (int off = 1; off < 256; off <<= 1) {
        int v = (tid >= off) ? sm[tid - off] : 0;
        __syncthreads();
        sm[tid] += v;
        __syncthreads();
    }
    int basep = bucket_base + ((tid == 0) ? 0 : sm[tid - 1]);
    int node0 = (b << BSH) + n0;
    int p0 = basep;
    int p1 = basep + tot0;
    if (node0 < NN) {
        if (c == 0) { offsets[node0] = p0; inv_cnt[node0] = 1.0f / (1.0f + (float)tot0); }
        cur[n0] = p0 + pre0;
    }
    if (node0 + 1 < NN) {
        if (c == 0) { offsets[node0 + 1] = p1; inv_cnt[node0 + 1] = 1.0f / (1.0f + (float)tot1); }
        cur[n1] = p1 + pre1;
    }
    __syncthreads();

    // place my chunk (~cnt/8 edges); writes land in this bucket's L2-resident window
    int cnt = gcursor[b];
    int cs = (cnt + NCHUNK - 1) >> 3;
    int lo = c * cs;
    int hi = lo + cs; if (hi > cnt) hi = cnt;
    const unsigned int* ePtr = binned + (size_t)b * BCAP;
    for (int j = lo + tid; j < hi; j += 256) {
        unsigned int v = ePtr[j];
        int pos = atomicAdd(&cur[v >> 20], 1);
        col[pos] = (int)(v & 0xFFFFF);
    }
}

// ---------- shared gather+conv body (one wave per node) ----------
__device__ __forceinline__ void gather_conv_node(
    const f16x8* __restrict__ xin, const int* __restrict__ offsets,
    const int* __restrict__ col, const float* __restrict__ inv_cnt,
    const float* wr, float bb, int node, int lane, int q, int p, float* s)
{
    int lo = offsets[node], hi = offsets[node + 1];
    int cnt = hi - lo;
    int my_col = (lane < cnt) ? col[lo + lane] : 0;
    int jn = cnt < 64 ? cnt : 64;

    const f16 z = (f16)0;
    f16x8 acc0 = {z, z, z, z, z, z, z, z};
    f16x8 acc1 = {z, z, z, z, z, z, z, z};

    int j = 0;
    for (; j + 7 < jn; j += 8) {               // 8 edges / iter, 2 loads in flight
        int c0 = __shfl(my_col, j + q);
        int c1 = __shfl(my_col, j + 4 + q);
        f16x8 v0 = xin[(c0 << 4) | p];
        f16x8 v1 = xin[(c1 << 4) | p];
        acc0 += v0;
        acc1 += v1;
    }
    for (; j + 3 < jn; j += 4) {               // 4 edges
        int c = __shfl(my_col, j + q);
        acc0 += xin[(c << 4) | p];
    }
    if (j < jn) {                              // tail 1..3 edges
        int rem = jn - j;
        int c = __shfl(my_col, j + (q < rem ? q : 0));
        f16x8 v = xin[(c << 4) | p];
        if (q < rem) acc1 += v;
    }
    for (int k = 64; k < cnt; k++) {           // degree > 64 (effectively never)
        int c = col[lo + k];
        f16x8 v = xin[(c << 4) | p];
        if (q == 0) acc0 += v;
    }
    acc0 += acc1;

    {   // combine the 4 quarter-groups: xor-16 then xor-32
        HU8 u; u.h = acc0;
        int4 o;
        o.x = __shfl_xor(u.i.x, 16); o.y = __shfl_xor(u.i.y, 16);
        o.z = __shfl_xor(u.i.z, 16); o.w = __shfl_xor(u.i.w, 16);
        HU8 w2; w2.i = o;
        acc0 += w2.h;
        u.h = acc0;
        o.x = __shfl_xor(u.i.x, 32); o.y = __shfl_xor(u.i.y, 32);
        o.z = __shfl_xor(u.i.z, 32); o.w = __shfl_xor(u.i.w, 32);
        w2.i = o;
        acc0 += w2.h;
    }

    // fp32 epilogue: + self row, conv K=9, mean, bias, relu
    f16x8 sv = xin[(node << 4) | p];
    float A[16];
    A[4]  = (float)acc0[0] + (float)sv[0];
    A[5]  = (float)acc0[1] + (float)sv[1];
    A[6]  = (float)acc0[2] + (float)sv[2];
    A[7]  = (float)acc0[3] + (float)sv[3];
    A[8]  = (float)acc0[4] + (float)sv[4];
    A[9]  = (float)acc0[5] + (float)sv[5];
    A[10] = (float)acc0[6] + (float)sv[6];
    A[11] = (float)acc0[7] + (float)sv[7];
#pragma unroll
    for (int i = 0; i < 4; i++) {
        A[i]      = __shfl_up(A[8 + i], 1, 16);    // prev lane's a[4..7]
        A[12 + i] = __shfl_down(A[4 + i], 1, 16);  // next lane's a[0..3]
    }
    if (p == 0)  { A[0] = 0.0f; A[1] = 0.0f; A[2] = 0.0f; A[3] = 0.0f; }
    if (p == 15) { A[12] = 0.0f; A[13] = 0.0f; A[14] = 0.0f; A[15] = 0.0f; }

    float ic = inv_cnt[node];
#pragma unroll
    for (int i = 0; i < 8; i++) {
        float t = 0.0f;
#pragma unroll
        for (int k = 0; k < KK; k++) t += wr[k] * A[i + k];
        s[i] = fmaxf(t * ic + bb, 0.0f);
    }
}

// ---------- layers: 256-thr blocks, 4 nodes/block (proven 62.5 us config) ----------
__global__ void fused_layer_kernel(const f16x8* __restrict__ xin,
                                   const int* __restrict__ offsets,
                                   const int* __restrict__ col,
                                   const float* __restrict__ inv_cnt,
                                   const float* __restrict__ w9,
                                   const float* __restrict__ bptr,
                                   f16x8* __restrict__ yout) {
    int tid = threadIdx.x;
    int lane = tid & 63;
    int q = lane >> 4;
    int p = lane & 15;
    int node = blockIdx.x * 4 + (tid >> 6);
    float wr[KK];
#pragma unroll
    for (int k = 0; k < KK; k++) wr[k] = w9[k];
    float s[8];
    gather_conv_node(xin, offsets, col, inv_cnt, wr, bptr[0], node, lane, q, p, s);
    if (q == 0) {
        f16x8 o;
#pragma unroll
        for (int i = 0; i < 8; i++) o[i] = (f16)s[i];
        yout[(node << 4) | p] = o;
    }
}

// ---------- output head, stage 1: partial[t][sp] = dot(y3flat[t, n-slice], Wout[, n-slice]) ----------
__global__ void out_partial_kernel(const f16* __restrict__ y3,
                                   const float* __restrict__ Wout,
                                   float* __restrict__ partial) {
    __shared__ float red[4][3];
    int sp = blockIdx.x;
    int tg = blockIdx.y;
    int tid = threadIdx.x;
    int lane = tid & 63;
    int wave = tid >> 6;
    int n0 = sp * OSLICE;
    int n1 = n0 + OSLICE;
    if (n1 > NN) n1 = NN;
    for (int t = tg * 8; t < tg * 8 + 8; t++) {
        const f16* yrow = y3 + (size_t)t * NN;
        float a0 = 0.0f, a1 = 0.0f, a2 = 0.0f;
        for (int n = n0 + tid * 2; n < n1; n += 512) {
            f16x2 v = *(const f16x2*)(yrow + n);
            float vx = (float)v.x, vy = (float)v.y;
            float2 wA = *(const float2*)(Wout + n);
            float2 wB = *(const float2*)(Wout + NN + n);
            float2 wC = *(const float2*)(Wout + 2 * NN + n);
            a0 += vx * wA.x + vy * wA.y;
            a1 += vx * wB.x + vy * wB.y;
            a2 += vx * wC.x + vy * wC.y;
        }
        for (int o = 32; o > 0; o >>= 1) {
            a0 += __shfl_down(a0, o);
            a1 += __shfl_down(a1, o);
            a2 += __shfl_down(a2, o);
        }
        if (lane == 0) {
            red[wave][0] = a0;
            red[wave][1] = a1;
            red[wave][2] = a2;
        }
        __syncthreads();
        if (tid == 0) {
            int idx = (t * ONS + sp) * 3;
            partial[idx + 0] = red[0][0] + red[1][0] + red[2][0] + red[3][0];
            partial[idx + 1] = red[0][1] + red[1][1] + red[2][1] + red[3][1];
            partial[idx + 2] = red[0][2] + red[1][2] + red[2][2] + red[3][2];
        }
        __syncthreads();
    }
}

// ---------- output head, stage 2: out[t][c] = bias[c] + sum_sp partial[t][sp][c] ----------
__global__ void out_reduce_kernel(const float* __restrict__ partial,
                                  const float* __restrict__ bout,
                                  float* __restrict__ out) {
    int t = blockIdx.x;
    int l = threadIdx.x;    // 64
    int idx = (t * ONS + l) * 3;
    float a0 = partial[idx + 0];
    float a1 = partial[idx + 1];
    float a2 = partial[idx + 2];
    for (int o = 32; o > 0; o >>= 1) {
        a0 += __shfl_down(a0, o);
        a1 += __shfl_down(a1, o);
        a2 += __shfl_down(a2, o);
    }
    if (l == 0) {
        out[t * 3 + 0] = bout[0] + a0;
        out[t * 3 + 1] = bout[1] + a1;
        out[t * 3 + 2] = bout[2] + a2;
    }
}

extern "C" void kernel_launch(void* const* d_in, const int* in_sizes, int n_in,
                              void* d_out, int out_size, void* d_ws, size_t ws_size,
                              hipStream_t stream) {
    const float4* x    = (const float4*)d_in[0];  // [N,T]
    const int*    ei   = (const int*)d_in[1];     // [2,E]
    const float*  cw   = (const float*)d_in[2];   // [L,1,1,K]
    const float*  cb   = (const float*)d_in[3];   // [L,1]
    const float*  Wout = (const float*)d_in[4];   // [3,N]
    const float*  bout = (const float*)d_in[5];   // [3]
    float* out = (float*)d_out;                   // [T,3]

    char* ws = (char*)d_ws;
    size_t off = 0;
    auto alloc = [&](size_t bytes) -> void* {
        void* p = ws + off;
        off += (bytes + 255) & ~(size_t)255;
        return p;
    };
    f16x8*        x16       = (f16x8*)alloc((size_t)NN * TT * 2);
    f16x8*        yA        = (f16x8*)alloc((size_t)NN * TT * 2);
    f16x8*        yB        = (f16x8*)alloc((size_t)NN * TT * 2);
    unsigned int* binned    = (unsigned int*)alloc((size_t)NBUCK * BCAP * 4);
    int*          gcursor   = (int*)alloc((size_t)NBUCK * 4);
    int*          chunkhist = (int*)alloc((size_t)NBUCK * NCHUNK * 512 * 4);
    int*          offsets   = (int*)alloc((size_t)(NN + 1) * 4);
    float*        inv_cnt   = (float*)alloc((size_t)NN * 4);
    int*          col       = (int*)alloc((size_t)EE * 4);
    float*        partial   = (float*)alloc((size_t)TT * ONS * 3 * 4);

    // CSR build + cvt (ws/out are re-poisoned before every call)
    hipMemsetAsync(gcursor, 0, (size_t)NBUCK * 4, stream);
    bin_cvt_kernel<<<BINB + CVTB, 1024, 0, stream>>>(ei, gcursor, binned, x, (f16x4*)x16);
    chunk_hist_kernel<<<NBUCK * NCHUNK, 256, 0, stream>>>(binned, gcursor, chunkhist);
    bucket_place_kernel<<<NBUCK * NCHUNK, 256, 0, stream>>>(binned, gcursor, chunkhist,
                                                            offsets, inv_cnt, col);

    // 3 fused layers (conv commuted past gather; bias/mean folded exactly)
    fused_layer_kernel<<<NN / 4, 256, 0, stream>>>(x16, offsets, col, inv_cnt,
                                                   cw + 0 * KK, cb + 0, yA);
    fused_layer_kernel<<<NN / 4, 256, 0, stream>>>(yA, offsets, col, inv_cnt,
                                                   cw + 1 * KK, cb + 1, yB);
    fused_layer_kernel<<<NN / 4, 256, 0, stream>>>(yB, offsets, col, inv_cnt,
                                                   cw + 2 * KK, cb + 2, yA);

    // output head: y3/Wout read ~once; partials via plain stores, then tiny reduce
    out_partial_kernel<<<dim3(ONS, OTG), 256, 0, stream>>>((const f16*)yA, Wout, partial);
    out_reduce_kernel<<<TT, 64, 0, stream>>>(partial, bout, out);
}